// Round 3
// baseline (152.415 us; speedup 1.0000x reference)
//
#include <hip/hip_runtime.h>

// ============================================================================
// ROUND 3: DIAGNOSTIC BUILD — kernel logic identical to round 2 (verified
// passing). protonet_main is launched TWICE (idempotent: writes only `out`
// from immutable inputs). dur_us_R3 - dur_us_R2 = true main-kernel duration,
// which the harness's top-5 dispatch report hides below the 41 us poison
// fills. Next round reverts to single launch.
// ============================================================================

#define D_IN   1024
#define D_PROJ 256
#define N_C    64
#define N_ROWS 16384
#define BM     32
#define BK     64
#define A_STRIDE 72     // BK + 8 pad (bf16 elems) -> 144 B rows, uniform banks
#define Z_STRIDE 264    // D_PROJ + 8 pad -> 528 B rows
#define BSZ (D_PROJ * BK)     // shorts per B buffer (16384 = 32 KB)
#define ASZ (BM * A_STRIDE)   // shorts per A buffer (2304)

typedef float v4f __attribute__((ext_vector_type(4)));
typedef short v8s __attribute__((ext_vector_type(8)));

__device__ inline unsigned short f2bf(float f) {
  unsigned int u = __float_as_uint(f);
  u = u + 0x7fffu + ((u >> 16) & 1u);   // round-to-nearest-even
  return (unsigned short)(u >> 16);
}

__device__ inline void async16(const void* g, void* s) {
  __builtin_amdgcn_global_load_lds(
      (const __attribute__((address_space(1))) unsigned int*)g,
      (__attribute__((address_space(3))) unsigned int*)s, 16, 0, 0);
}

// counted-vmcnt barrier: drains lgkm (A ds_write) + all but N newest VMEM ops.
#define KBAR(N) do {                                                     \
  asm volatile("s_waitcnt vmcnt(" #N ") lgkmcnt(0)" ::: "memory");       \
  __builtin_amdgcn_s_barrier();                                          \
  __builtin_amdgcn_sched_barrier(0);                                     \
} while (0)

// ---------------------------------------------------------------------------
// Prep: projT bf16 [256][1024] (transposed), protoB bf16 [64][256], pnorm2[64],
//       mu_p[256] = mean @ proj (fp32)
// grid 96 x 256: blocks 0..63 transpose, 64..79 protos, 80..95 mu_p
// ---------------------------------------------------------------------------
__global__ __launch_bounds__(256) void prep_kernel(
    const float* __restrict__ proj,      // [1024][256]
    const float* __restrict__ protos,    // [64][256]
    const float* __restrict__ mean,      // [1024]
    unsigned short* __restrict__ projT,  // [256][1024]
    unsigned short* __restrict__ protoB, // [64][256]
    float* __restrict__ pnorm2,          // [64]
    float* __restrict__ mu_p)            // [256]
{
  __shared__ float tile[64][65];
  __shared__ float part[16][17];
  const int b = blockIdx.x;
  const int t = threadIdx.x;
  if (b < 64) {
    const int k0 = (b & 15) * 64, n0 = (b >> 4) * 64;
    const int r = t >> 4, c4 = (t & 15) * 4;
    for (int rr = r; rr < 64; rr += 16) {
      const float4 v = *(const float4*)(proj + (k0 + rr) * D_PROJ + n0 + c4);
      tile[rr][c4 + 0] = v.x; tile[rr][c4 + 1] = v.y;
      tile[rr][c4 + 2] = v.z; tile[rr][c4 + 3] = v.w;
    }
    __syncthreads();
    const int n = t >> 2, kc = (t & 3) * 16;
    unsigned short o[16];
#pragma unroll
    for (int i = 0; i < 16; ++i) o[i] = f2bf(tile[kc + i][n]);
    unsigned short* dst = projT + (n0 + n) * D_IN + k0 + kc;
#pragma unroll
    for (int i = 0; i < 4; ++i) {
      ushort4 s4 = { o[4*i+0], o[4*i+1], o[4*i+2], o[4*i+3] };
      *(ushort4*)(dst + 4*i) = s4;
    }
  } else if (b < 80) {
    const int w = t >> 6, l = t & 63;
    const int c = (b - 64) * 4 + w;                    // proto 0..63
    const float4 v = *(const float4*)(protos + c * D_PROJ + l * 4);
    float ss = v.x*v.x + v.y*v.y + v.z*v.z + v.w*v.w;
#pragma unroll
    for (int m = 1; m < 64; m <<= 1) ss += __shfl_xor(ss, m);
    if (l == 0) pnorm2[c] = ss;
    ushort4 o = { f2bf(v.x), f2bf(v.y), f2bf(v.z), f2bf(v.w) };
    *(ushort4*)(protoB + c * D_PROJ + l * 4) = o;
  } else {
    // mu_p: 16 blocks x 16 cols each; 16-way k-split per col
    const int b2  = b - 80;
    const int col = b2 * 16 + (t & 15);
    const int ks  = t >> 4;
    float s = 0.0f;
    const int kb = ks * 64;
#pragma unroll 4
    for (int k = 0; k < 64; ++k)
      s = fmaf(mean[kb + k], proj[(kb + k) * D_PROJ + col], s);
    part[ks][t & 15] = s;
    __syncthreads();
    if (t < 16) {
      float acc = 0.0f;
#pragma unroll
      for (int i = 0; i < 16; ++i) acc += part[i][t];
      mu_p[b2 * 16 + t] = acc;
    }
  }
}

// ---------------------------------------------------------------------------
// Main fused kernel: 32 rows/block, 512 blocks, 512 threads (8 waves)
// (identical to round 2 — see journal; double-buffered B/A, 1 barrier/tile,
//  counted vmcnt keeps X prefetch in flight, protos direct from global)
// ---------------------------------------------------------------------------
__global__ __launch_bounds__(512, 4) void protonet_main(
    const float* __restrict__ X,               // [16384][1024]
    const unsigned short* __restrict__ projT,  // [256][1024] bf16
    const unsigned short* __restrict__ protoB, // [64][256]   bf16
    const float* __restrict__ pnorm2,          // [64]
    const float* __restrict__ mu_p,            // [256]
    float* __restrict__ out)                   // [16384][64]
{
  __shared__ unsigned short lds_A[2 * ASZ];   // 9.2 KB, padded, double-buffered
  __shared__ unsigned short lds_B[2 * BSZ];   // 64 KB, swizzled, double-buffered
  __shared__ float lds_part[4][BM];
  __shared__ float lds_inv[BM];
  __shared__ float lds_z2[BM];

  const int t  = threadIdx.x;
  const int w  = t >> 6;
  const int l  = t & 63;
  const int q  = l >> 4;
  const int lc = l & 15;
  const int rg = w >> 2;      // 0..1 row group (16 rows)
  const int cg = w & 3;       // 0..3 col group (64 cols) / proto group (16)
  const int row0 = blockIdx.x * BM;

  // per-lane invariant src index for B staging:
  // instr s: row n = 32w + 8s + (l>>3), phys chunk p = l&7, logical = p^(n&7)
  const int bsrc0 = ((w << 5) + (l >> 3)) * D_IN + (((l & 7) ^ ((l >> 3) & 7)) << 3);
  const int bdst0 = (w << 5) * BK;   // + (s<<3)*BK per instr

  // A: thread owns row ar, float4 slot aj
  const int ar = t >> 4;
  const int aj = t & 15;
  const float* xbase = X + (row0 + ar) * D_IN + (aj << 2);

  ushort4 abf[16];     // bf16 A slices, one per k-tile (32 VGPRs)
  float4  xf[4];       // in-flight X chunk (16 VGPRs)

  // ---- prologue: load+convert chunk0, stage tile0 into buf0 ----
#pragma unroll
  for (int i = 0; i < 4; ++i) xf[i] = *(const float4*)(xbase + i * BK);
#pragma unroll
  for (int i = 0; i < 4; ++i) {
    const float4 v = xf[i];
    ushort4 o = { f2bf(v.x), f2bf(v.y), f2bf(v.z), f2bf(v.w) };
    abf[i] = o;
  }
#pragma unroll
  for (int s = 0; s < 4; ++s)
    async16(projT + bsrc0 + s * (8 * D_IN), lds_B + bdst0 + (s << 3) * BK);
  *(ushort4*)(lds_A + ar * A_STRIDE + (aj << 2)) = abf[0];
  __syncthreads();

  v4f acc1[4];
#pragma unroll
  for (int j = 0; j < 4; ++j) acc1[j] = (v4f)(0.0f);

#pragma unroll
  for (int kt = 0; kt < 16; ++kt) {
    const int cur = kt & 1;
    const int nxt = cur ^ 1;
    if (kt < 15) {
      // ---- stage tile kt+1 into buf nxt (B first: oldest VMEM ops) ----
#pragma unroll
      for (int s = 0; s < 4; ++s)
        async16(projT + bsrc0 + s * (8 * D_IN) + (kt + 1) * BK,
                lds_B + nxt * BSZ + bdst0 + (s << 3) * BK);
      // X prefetch: chunk c issued at kt = 4c-2 (AFTER B -> newest 4 VMEM ops)
      if ((kt & 3) == 2 && kt < 12) {
        const int c = (kt + 2) >> 2;
#pragma unroll
        for (int i = 0; i < 4; ++i)
          xf[i] = *(const float4*)(xbase + ((c << 2) + i) * BK);
      }
      // convert chunk c = (kt+1)/4 just-in-time for its first A ds_write
      if ((kt & 3) == 3) {
        const int c = (kt + 1) >> 2;
#pragma unroll
        for (int i = 0; i < 4; ++i) {
          const float4 v = xf[i];
          ushort4 o = { f2bf(v.x), f2bf(v.y), f2bf(v.z), f2bf(v.w) };
          abf[(c << 2) + i] = o;
        }
      }
      *(ushort4*)(lds_A + nxt * ASZ + ar * A_STRIDE + (aj << 2)) = abf[kt + 1];
    }
    // ---- compute tile kt from buf cur ----
    {
      const unsigned short* Ab = lds_A + cur * ASZ;
      const unsigned short* Bb = lds_B + cur * BSZ;
#pragma unroll
      for (int kk = 0; kk < 2; ++kk) {
        v8s a, bf[4];
        a = *(const v8s*)(Ab + ((rg << 4) + lc) * A_STRIDE + (kk << 5) + (q << 3));
#pragma unroll
        for (int j = 0; j < 4; ++j) {
          const int nb = (cg << 6) + (j << 4) + lc;
          const int p  = ((kk << 2) + q) ^ (lc & 7);
          bf[j] = *(const v8s*)(Bb + nb * BK + (p << 3));
        }
#pragma unroll
        for (int j = 0; j < 4; ++j)
          acc1[j] = __builtin_amdgcn_mfma_f32_16x16x32_bf16(a, bf[j], acc1[j], 0, 0, 0);
      }
    }
    // ---- one barrier per tile; keep X prefetch (4 newest) in flight ----
    if (kt < 15) {
      if (kt == 2 || kt == 6 || kt == 10) { KBAR(4); } else { KBAR(0); }
    }
  }

  // ---- Zc = Zraw - mu_p -> LDS bf16 (buf0 region) + fp32 row norms ----
  unsigned short* lds_Z = lds_B;
  float mu[4];
#pragma unroll
  for (int j = 0; j < 4; ++j) mu[j] = mu_p[(cg << 6) + (j << 4) + lc];
#pragma unroll
  for (int r = 0; r < 4; ++r) {
    float s2 = 0.0f;
    const int row = (rg << 4) + (q << 2) + r;
#pragma unroll
    for (int j = 0; j < 4; ++j) {
      const float v = acc1[j][r] - mu[j];
      s2 += v * v;
      lds_Z[row * Z_STRIDE + (cg << 6) + (j << 4) + lc] = f2bf(v);
    }
    s2 += __shfl_xor(s2, 1);
    s2 += __shfl_xor(s2, 2);
    s2 += __shfl_xor(s2, 4);
    s2 += __shfl_xor(s2, 8);
    if (lc == 0) lds_part[cg][row] = s2;
  }
  __syncthreads();
  if (t < BM) {
    const float n2  = lds_part[0][t] + lds_part[1][t] + lds_part[2][t] + lds_part[3][t];
    const float nrm = sqrtf(n2);
    const float inv = 1.0f / fmaxf(nrm, 1e-12f);   // torch/jax normalize eps
    lds_inv[t] = inv;
    lds_z2[t]  = n2 * inv * inv;                   // == 1 unless degenerate
  }
  __syncthreads();

  // ---- GEMM2: dot(Zc, proto_c); wave (rg, pg=cg): 16 rows x 16 protos ----
  v8s pb[8];
  {
    const unsigned short* prow = protoB + ((cg << 4) + lc) * D_PROJ + (q << 3);
#pragma unroll
    for (int kk = 0; kk < 8; ++kk)
      pb[kk] = *(const v8s*)(prow + (kk << 5));
  }
  v4f acc2 = (v4f)(0.0f);
#pragma unroll
  for (int kk = 0; kk < 8; ++kk) {
    v8s za = *(const v8s*)(lds_Z + ((rg << 4) + lc) * Z_STRIDE + (kk << 5) + (q << 3));
    acc2 = __builtin_amdgcn_mfma_f32_16x16x32_bf16(za, pb[kk], acc2, 0, 0, 0);
  }

  // ---- epilogue: d^2 = ||Z||^2 + ||p||^2 - 2*dot*inv ; score = -sqrt(d^2) ----
  const int c  = (cg << 4) + lc;
  const float pn = pnorm2[c];
#pragma unroll
  for (int r = 0; r < 4; ++r) {
    const int row = (rg << 4) + (q << 2) + r;
    const float inv = lds_inv[row];
    const float d2  = lds_z2[row] + pn - 2.0f * acc2[r] * inv;
    out[(row0 + row) * N_C + c] = -sqrtf(fmaxf(d2, 0.0f));
  }
}

extern "C" void kernel_launch(void* const* d_in, const int* in_sizes, int n_in,
                              void* d_out, int out_size, void* d_ws, size_t ws_size,
                              hipStream_t stream) {
  const float* X      = (const float*)d_in[0];
  const float* protos = (const float*)d_in[1];
  const float* mean   = (const float*)d_in[2];
  const float* proj   = (const float*)d_in[3];
  float* out = (float*)d_out;

  unsigned short* projT  = (unsigned short*)d_ws;          // 256*1024 bf16 = 512 KB
  unsigned short* protoB = projT + D_PROJ * D_IN;          // 64*256  bf16 = 32 KB
  float*          pn2    = (float*)(protoB + N_C * D_PROJ);// 64 fp32
  float*          mup    = pn2 + N_C;                      // 256 fp32

  prep_kernel<<<96, 256, 0, stream>>>(proj, protos, mean, projT, protoB, pn2, mup);
  protonet_main<<<N_ROWS / BM, 512, 0, stream>>>(X, projT, protoB, pn2, mup, out);
  // DIAGNOSTIC: second identical launch (idempotent). dur_us delta vs round 2
  // == true protonet_main duration, invisible in the top-5 dispatch report.
  protonet_main<<<N_ROWS / BM, 512, 0, stream>>>(X, projT, protoB, pn2, mup, out);
}

// Round 4
// 132.925 us; speedup vs baseline: 1.1466x; 1.1466x over previous
//
#include <hip/hip_runtime.h>

// ============================================================================
// R4: B operand (projT) read L2->VGPR directly (16B frags are contiguous in
// projT; one dwordx4 = 16 fully-used 64B lines). LDS holds only A (4-tile
// group, single-buffered) + Z. 8 lgkm-only barriers in the k-loop, zero
// vmcnt drains -> X/B loads stay in flight across barriers.
// Diagnosis R3: main kernel = 31 us (152.4 double-launch - 121.2 single);
// LDS pipe was ~940 MB (B dup reads + staging writes) -> now ~290 MB.
// ============================================================================

#define D_IN   1024
#define D_PROJ 256
#define N_C    64
#define N_ROWS 16384
#define BM     32
#define A_STRIDE 72         // 64 + 8 pad shorts -> 144 B rows
#define ATS (32 * A_STRIDE) // shorts per A k-tile buffer (2304)
#define Z_STRIDE 264        // D_PROJ + 8 pad

typedef float v4f __attribute__((ext_vector_type(4)));
typedef short v8s __attribute__((ext_vector_type(8)));

__device__ inline unsigned short f2bf(float f) {
  unsigned int u = __float_as_uint(f);
  u = u + 0x7fffu + ((u >> 16) & 1u);   // round-to-nearest-even
  return (unsigned short)(u >> 16);
}

// lgkm-only barrier: A ds_write/ds_read ordering WITHOUT draining vmcnt,
// so in-flight X (HBM) and B (L2) loads survive the barrier.
#define GBAR() do {                                              \
  asm volatile("s_waitcnt lgkmcnt(0)" ::: "memory");             \
  __builtin_amdgcn_s_barrier();                                  \
  __builtin_amdgcn_sched_barrier(0);                             \
} while (0)

// ---------------------------------------------------------------------------
// Prep (unchanged): projT bf16 [256][1024], protoB bf16 [64][256], pnorm2[64],
// mu_p[256] = mean @ proj
// ---------------------------------------------------------------------------
__global__ __launch_bounds__(256) void prep_kernel(
    const float* __restrict__ proj,      // [1024][256]
    const float* __restrict__ protos,    // [64][256]
    const float* __restrict__ mean,      // [1024]
    unsigned short* __restrict__ projT,  // [256][1024]
    unsigned short* __restrict__ protoB, // [64][256]
    float* __restrict__ pnorm2,          // [64]
    float* __restrict__ mu_p)            // [256]
{
  __shared__ float tile[64][65];
  __shared__ float part[16][17];
  const int b = blockIdx.x;
  const int t = threadIdx.x;
  if (b < 64) {
    const int k0 = (b & 15) * 64, n0 = (b >> 4) * 64;
    const int r = t >> 4, c4 = (t & 15) * 4;
    for (int rr = r; rr < 64; rr += 16) {
      const float4 v = *(const float4*)(proj + (k0 + rr) * D_PROJ + n0 + c4);
      tile[rr][c4 + 0] = v.x; tile[rr][c4 + 1] = v.y;
      tile[rr][c4 + 2] = v.z; tile[rr][c4 + 3] = v.w;
    }
    __syncthreads();
    const int n = t >> 2, kc = (t & 3) * 16;
    unsigned short o[16];
#pragma unroll
    for (int i = 0; i < 16; ++i) o[i] = f2bf(tile[kc + i][n]);
    unsigned short* dst = projT + (n0 + n) * D_IN + k0 + kc;
#pragma unroll
    for (int i = 0; i < 4; ++i) {
      ushort4 s4 = { o[4*i+0], o[4*i+1], o[4*i+2], o[4*i+3] };
      *(ushort4*)(dst + 4*i) = s4;
    }
  } else if (b < 80) {
    const int w = t >> 6, l = t & 63;
    const int c = (b - 64) * 4 + w;                    // proto 0..63
    const float4 v = *(const float4*)(protos + c * D_PROJ + l * 4);
    float ss = v.x*v.x + v.y*v.y + v.z*v.z + v.w*v.w;
#pragma unroll
    for (int m = 1; m < 64; m <<= 1) ss += __shfl_xor(ss, m);
    if (l == 0) pnorm2[c] = ss;
    ushort4 o = { f2bf(v.x), f2bf(v.y), f2bf(v.z), f2bf(v.w) };
    *(ushort4*)(protoB + c * D_PROJ + l * 4) = o;
  } else {
    const int b2  = b - 80;
    const int col = b2 * 16 + (t & 15);
    const int ks  = t >> 4;
    float s = 0.0f;
    const int kb = ks * 64;
#pragma unroll 4
    for (int k = 0; k < 64; ++k)
      s = fmaf(mean[kb + k], proj[(kb + k) * D_PROJ + col], s);
    part[ks][t & 15] = s;
    __syncthreads();
    if (t < 16) {
      float acc = 0.0f;
#pragma unroll
      for (int i = 0; i < 16; ++i) acc += part[i][t];
      mu_p[b2 * 16 + t] = acc;
    }
  }
}

// ---------------------------------------------------------------------------
// Main: 32 rows/block, 512 blocks, 512 threads (8 waves).
// GEMM1: wave w owns 32 rows x 32 cols (cols w*32..w*32+31).
//   step s (0..31): kt = s>>1, kk = s&1. Per step: prefetch B pair for s+1
//   (global, 2x16B), read 2 A frags (LDS), 4x mfma_16x16x32.
//   A staged in 4-tile groups; 2 lgkm-only barriers per group.
// GEMM2 + epilogue: unchanged from R2 (verified).
// ---------------------------------------------------------------------------
__global__ __launch_bounds__(512, 4) void protonet_main(
    const float* __restrict__ X,               // [16384][1024]
    const unsigned short* __restrict__ projT,  // [256][1024] bf16
    const unsigned short* __restrict__ protoB, // [64][256]   bf16
    const float* __restrict__ pnorm2,          // [64]
    const float* __restrict__ mu_p,            // [256]
    float* __restrict__ out)                   // [16384][64]
{
  __shared__ unsigned short lds_A[4 * ATS];       // 18.4 KB: 4 k-tiles
  __shared__ unsigned short lds_Z[BM * Z_STRIDE]; // 16.9 KB
  __shared__ float lds_part[8][BM];
  __shared__ float lds_inv[BM];
  __shared__ float lds_z2[BM];

  const int t  = threadIdx.x;
  const int w  = t >> 6;
  const int l  = t & 63;
  const int q  = l >> 4;
  const int lc = l & 15;
  const int row0 = blockIdx.x * BM;

  // A staging: thread owns row ar, 4-float slot aj
  const int ar = t >> 4;
  const int aj = t & 15;
  const float* xbase = X + (row0 + ar) * D_IN + (aj << 2);
  unsigned short* awr = lds_A + ar * A_STRIDE + (aj << 2);

  // B fragment base: col = w*32 + lc (j=0) / +16 (j=1), k-offset q*8
  const unsigned short* bp0 = projT + ((w << 5) + lc) * D_IN + (q << 3);

  float4  xf[4];       // in-flight X chunk (4 k-tiles worth per thread)
  ushort4 abf[4];      // converted A slices for current group
  v8s     bf[2][2];    // B prefetch: [step parity][j]
  v4f     acc1[4];     // [rg*2+j]: rows rg*16+, cols w*32+j*16+

#pragma unroll
  for (int j = 0; j < 4; ++j) acc1[j] = (v4f)(0.0f);

  // B pair for step S -> bf[S&1]; offsets are compile-time after unroll
#define LOADB(S) do {                                                         \
    bf[(S) & 1][0] = *(const v8s*)(bp0 + (((S) >> 1) << 6) + (((S) & 1) << 5));\
    bf[(S) & 1][1] = *(const v8s*)(bp0 + (D_IN << 4) +                        \
                                   (((S) >> 1) << 6) + (((S) & 1) << 5));     \
  } while (0)

#define STEP(S) do {                                                          \
    if ((S) < 31) LOADB((S) + 1);                                             \
    const unsigned short* At_ = lds_A + (((S) >> 1) & 3) * ATS +              \
                                (((S) & 1) << 5) + (q << 3);                  \
    v8s a0_ = *(const v8s*)(At_ + lc * A_STRIDE);                             \
    v8s a1_ = *(const v8s*)(At_ + (16 + lc) * A_STRIDE);                      \
    acc1[0] = __builtin_amdgcn_mfma_f32_16x16x32_bf16(a0_, bf[(S)&1][0], acc1[0], 0, 0, 0); \
    acc1[1] = __builtin_amdgcn_mfma_f32_16x16x32_bf16(a0_, bf[(S)&1][1], acc1[1], 0, 0, 0); \
    acc1[2] = __builtin_amdgcn_mfma_f32_16x16x32_bf16(a1_, bf[(S)&1][0], acc1[2], 0, 0, 0); \
    acc1[3] = __builtin_amdgcn_mfma_f32_16x16x32_bf16(a1_, bf[(S)&1][1], acc1[3], 0, 0, 0); \
  } while (0)

  // ---- prologue: X chunk0 -> convert -> issue chunk1 -> write group 0 ----
#pragma unroll
  for (int i = 0; i < 4; ++i) xf[i] = *(const float4*)(xbase + (i << 6));
  LOADB(0);                                   // issued after xf0: survives cvt wait
#pragma unroll
  for (int i = 0; i < 4; ++i) {
    const float4 v = xf[i];
    ushort4 o = { f2bf(v.x), f2bf(v.y), f2bf(v.z), f2bf(v.w) };
    abf[i] = o;
  }
#pragma unroll
  for (int i = 0; i < 4; ++i) xf[i] = *(const float4*)(xbase + ((4 + i) << 6));
#pragma unroll
  for (int i = 0; i < 4; ++i) *(ushort4*)(awr + i * ATS) = abf[i];
  GBAR();

  // ---- k-loop: 4 groups x (8 steps + A re-stage) ----
#pragma unroll
  for (int g = 0; g < 4; ++g) {
#pragma unroll
    for (int s8 = 0; s8 < 8; ++s8) STEP(g * 8 + s8);
    if (g < 3) {
      // convert chunk g+1 (loaded a full group ago; waits only its own vmcnt)
#pragma unroll
      for (int i = 0; i < 4; ++i) {
        const float4 v = xf[i];
        ushort4 o = { f2bf(v.x), f2bf(v.y), f2bf(v.z), f2bf(v.w) };
        abf[i] = o;
      }
      if (g < 2) {
#pragma unroll
        for (int i = 0; i < 4; ++i)
          xf[i] = *(const float4*)(xbase + (((g + 2) * 4 + i) << 6));
      }
      GBAR();                                 // all reads of group g done
#pragma unroll
      for (int i = 0; i < 4; ++i) *(ushort4*)(awr + i * ATS) = abf[i];
      GBAR();                                 // group g+1 A visible
    }
  }

  // ---- Zc = Zraw - mu_p -> lds_Z bf16 + fp32 row norms ----
  const float mu0 = mu_p[(w << 5) + lc];
  const float mu1 = mu_p[(w << 5) + 16 + lc];
#pragma unroll
  for (int rg = 0; rg < 2; ++rg) {
#pragma unroll
    for (int r = 0; r < 4; ++r) {
      const int row = (rg << 4) + (q << 2) + r;
      const float v0 = acc1[rg * 2 + 0][r] - mu0;
      const float v1 = acc1[rg * 2 + 1][r] - mu1;
      lds_Z[row * Z_STRIDE + (w << 5) + lc]      = f2bf(v0);
      lds_Z[row * Z_STRIDE + (w << 5) + 16 + lc] = f2bf(v1);
      float s2 = v0 * v0 + v1 * v1;
      s2 += __shfl_xor(s2, 1);
      s2 += __shfl_xor(s2, 2);
      s2 += __shfl_xor(s2, 4);
      s2 += __shfl_xor(s2, 8);
      if (lc == 0) lds_part[w][row] = s2;
    }
  }
  __syncthreads();
  if (t < BM) {
    float n2 = 0.0f;
#pragma unroll
    for (int i = 0; i < 8; ++i) n2 += lds_part[i][t];
    const float nrm = sqrtf(n2);
    const float inv = 1.0f / fmaxf(nrm, 1e-12f);   // torch/jax normalize eps
    lds_inv[t] = inv;
    lds_z2[t]  = n2 * inv * inv;                   // == 1 unless degenerate
  }
  __syncthreads();

  // ---- GEMM2: dot(Zc, proto_c); wave (rg2, cg2): 16 rows x 16 protos ----
  const int rg2 = w >> 2;
  const int cg2 = w & 3;
  v8s pb[8];
  {
    const unsigned short* prow = protoB + ((cg2 << 4) + lc) * D_PROJ + (q << 3);
#pragma unroll
    for (int kk = 0; kk < 8; ++kk)
      pb[kk] = *(const v8s*)(prow + (kk << 5));
  }
  v4f acc2 = (v4f)(0.0f);
#pragma unroll
  for (int kk = 0; kk < 8; ++kk) {
    v8s za = *(const v8s*)(lds_Z + ((rg2 << 4) + lc) * Z_STRIDE + (kk << 5) + (q << 3));
    acc2 = __builtin_amdgcn_mfma_f32_16x16x32_bf16(za, pb[kk], acc2, 0, 0, 0);
  }

  // ---- epilogue: d^2 = ||Z||^2 + ||p||^2 - 2*dot*inv ; score = -sqrt(d^2) ----
  const int c  = (cg2 << 4) + lc;
  const float pn = pnorm2[c];
#pragma unroll
  for (int r = 0; r < 4; ++r) {
    const int row = (rg2 << 4) + (q << 2) + r;
    const float inv = lds_inv[row];
    const float d2  = lds_z2[row] + pn - 2.0f * acc2[r] * inv;
    out[(row0 + row) * N_C + c] = -sqrtf(fmaxf(d2, 0.0f));
  }
}

extern "C" void kernel_launch(void* const* d_in, const int* in_sizes, int n_in,
                              void* d_out, int out_size, void* d_ws, size_t ws_size,
                              hipStream_t stream) {
  const float* X      = (const float*)d_in[0];
  const float* protos = (const float*)d_in[1];
  const float* mean   = (const float*)d_in[2];
  const float* proj   = (const float*)d_in[3];
  float* out = (float*)d_out;

  unsigned short* projT  = (unsigned short*)d_ws;          // 256*1024 bf16 = 512 KB
  unsigned short* protoB = projT + D_PROJ * D_IN;          // 64*256  bf16 = 32 KB
  float*          pn2    = (float*)(protoB + N_C * D_PROJ);// 64 fp32
  float*          mup    = pn2 + N_C;                      // 256 fp32

  prep_kernel<<<96, 256, 0, stream>>>(proj, protos, mean, projT, protoB, pn2, mup);
  protonet_main<<<N_ROWS / BM, 512, 0, stream>>>(X, projT, protoB, pn2, mup, out);
}